// Round 14
// baseline (743.534 us; speedup 1.0000x reference)
//
#include <hip/hip_runtime.h>
#include <hip/hip_bf16.h>

typedef float  f32x4  __attribute__((ext_vector_type(4)));
typedef __bf16 bf16x8 __attribute__((ext_vector_type(8)));
typedef __bf16 bf16x4 __attribute__((ext_vector_type(4)));

__device__ __forceinline__ float silu_f(float x) { return x / (1.0f + __expf(-x)); }

__device__ __forceinline__ void gload16(const __bf16* g, const char* lds) {
    __builtin_amdgcn_global_load_lds((const __attribute__((address_space(1))) void*)g,
                                     (__attribute__((address_space(3))) void*)lds, 16, 0, 0);
}

// ---------------- merged LN + weight transposes + rel-bias ----------------
__global__ __launch_bounds__(256) void prepln_kernel(const float* __restrict__ x,
                                                     const float* __restrict__ ln_g,
                                                     const float* __restrict__ ln_b,
                                                     __bf16* __restrict__ norm,
                                                     const float* __restrict__ W_h,
                                                     const float* __restrict__ W_qk,
                                                     const float* __restrict__ W_o,
                                                     const float* __restrict__ rel_emb,
                                                     __bf16* __restrict__ WhT,
                                                     __bf16* __restrict__ WqkT,
                                                     __bf16* __restrict__ WoT,
                                                     float* __restrict__ bmat) {
    __shared__ float red[8];
    __shared__ __bf16 tile[32][33];
    int id = blockIdx.x, tid = threadIdx.x;
    if (id < 16384) {                       // LayerNorm
        const float* xr = x + (long)id * 1024;
        f32x4 v = *(const f32x4*)(xr + tid * 4);
        float s  = v[0] + v[1] + v[2] + v[3];
        float ss = v[0]*v[0] + v[1]*v[1] + v[2]*v[2] + v[3]*v[3];
        #pragma unroll
        for (int off = 32; off > 0; off >>= 1) {
            s  += __shfl_down(s, off);
            ss += __shfl_down(ss, off);
        }
        int wave = tid >> 6, lane = tid & 63;
        if (lane == 0) { red[wave*2] = s; red[wave*2+1] = ss; }
        __syncthreads();
        float S  = red[0] + red[2] + red[4] + red[6];
        float SS = red[1] + red[3] + red[5] + red[7];
        float mean = S * (1.0f/1024.0f);
        float var  = SS * (1.0f/1024.0f) - mean*mean;
        float rstd = rsqrtf(var + 1e-5f);
        __bf16* orow = norm + (long)id * 1024;
        #pragma unroll
        for (int j = 0; j < 4; j++) {
            float fv = (v[j] - mean) * rstd * ln_g[tid*4+j] + ln_b[tid*4+j];
            orow[tid*4+j] = (__bf16)fv;
        }
        return;
    }
    id -= 16384;
    if (id >= 6272) {                       // relbias
        int idx = (id - 6272) * 256 + tid;
        int i = idx >> 8, j = idx & 255;
        int n = i - j;
        int ret = (n < 0) ? 16 : 0;
        int an = (n < 0) ? -n : n;
        int bucket;
        if (an < 8) {
            bucket = ret + an;
        } else {
            float vl = logf((float)an * 0.125f) / 2.772588722239781f * 8.0f;
            int lv = 8 + (int)vl;
            bucket = ret + (lv < 15 ? lv : 15);
        }
        bmat[idx] = rel_emb[bucket] * 11.313708498984761f;
        return;
    }
    const float* in; __bf16* outp; int rows, cols, tx, ty;
    if (id < 4096)      { in = W_h;  outp = WhT;  rows = 1024; cols = 4096; tx = id % 128; ty = id / 128; }
    else if (id < 4224) { int t = id - 4096; in = W_qk; outp = WqkT; rows = 1024; cols = 128;  tx = t % 4;  ty = t / 4; }
    else                { int t = id - 4224; in = W_o;  outp = WoT;  rows = 2048; cols = 1024; tx = t % 32; ty = t / 32; }
    int c0 = tx * 32, r0 = ty * 32;
    int lx = tid & 31, ly = tid >> 5;
    #pragma unroll
    for (int i = 0; i < 4; i++) {
        int r = ly + i*8;
        tile[r][lx] = (__bf16)in[(long)(r0 + r) * cols + c0 + lx];
    }
    __syncthreads();
    #pragma unroll
    for (int i = 0; i < 4; i++) {
        int c = ly + i*8;
        outp[(long)(c0 + c) * rows + r0 + lx] = tile[lx][c];
    }
}

// ---------------- reduce 8 bf16 partials -> bf16 ----------------
__global__ __launch_bounds__(256) void reduce8_kernel(const __bf16* __restrict__ in,
                                                      __bf16* __restrict__ out) {
    int i = (blockIdx.x * 256 + threadIdx.x) * 4;
    int b = i >> 18;
    int r = i & 262143;
    float s0 = 0.f, s1 = 0.f, s2 = 0.f, s3 = 0.f;
    #pragma unroll
    for (int c = 0; c < 8; ++c) {
        bf16x4 v = *(const bf16x4*)(in + ((long)(b*8 + c) << 18) + r);
        s0 += (float)v[0]; s1 += (float)v[1]; s2 += (float)v[2]; s3 += (float)v[3];
    }
    bf16x4 o; o[0] = (__bf16)s0; o[1] = (__bf16)s1; o[2] = (__bf16)s2; o[3] = (__bf16)s3;
    *(bf16x4*)(out + i) = o;
}

// ---------------- GP param block ----------------
struct GP {
    const __bf16* A;
    const __bf16* B;
    const __bf16* A2;
    const __bf16* B2;
    int lda, ldb, kSteps;
    long sAz, sBz, sCz;
    float scale;
    float* outF;
    __bf16 *o0, *o1, *o2, *o3, *o4, *o5;
    const float *c0, *c1, *c2, *c3;
    __bf16* gbuf;
};

// ================= 256x128 GEMM, BK=64, 4 waves M-stacked, 48KB LDS =================
// C[m][n] = sum_k A[m][k]*B[n][k]. Wave w owns rows [w*64,(w+1)*64) x all 128 cols:
// acc[4][8] (128 VGPR). Per K-step per wave: 12 gloads, 24 ds_reads, 64 MFMA,
// 2 barriers -> 2x the MFMA-per-barrier of the 128^2 kernel.
// EPI 0: hqk merged (by<32 -> hidden silu->vT/gate; by==32 -> qk 4 heads).
// EPI 6: final = acc + b_o + x (fp32).
template<int EPI>
__global__ __launch_bounds__(256) void g256x128_kernel(GP p) {
    __shared__ __bf16 As[2*256*32];   // 32KB: [kk][256][32]
    __shared__ __bf16 Bs[2*128*32];   // 16KB: [kk][128][32]
    int bx = blockIdx.x, by = blockIdx.y;
    const bool qkm = (EPI == 0) && (by == 32);
    const __bf16* A = p.A + (long)bx * 256 * p.lda;
    const __bf16* B = qkm ? p.B2 : p.B + (long)by * 128 * p.ldb;
    int tid = threadIdx.x;
    int wave = tid >> 6, lane = tid & 63;
    int lr = lane & 15, kg = lane >> 4;

    f32x4 acc[4][8] = {};

    int lsub = lane >> 2;
    int scol = (lane & 3) * 8;
    const __bf16* AgW = A + scol + (long)(wave*64 + lsub) * p.lda;
    const __bf16* BgW = B + scol + (long)(wave*32 + lsub) * p.ldb;
    const long lda = p.lda, ldb = p.ldb;

    for (int ks = 0; ks < p.kSteps; ++ks) {
        long k0 = (long)ks * 64;
        __syncthreads();
#pragma unroll
        for (int kk = 0; kk < 2; ++kk) {
            const __bf16* sA = AgW + k0 + kk*32;
            const char* dA = (const char*)As + kk*16384 + wave*4096;
            gload16(sA,           dA);
            gload16(sA + 16*lda,  dA + 1024);
            gload16(sA + 32*lda,  dA + 2048);
            gload16(sA + 48*lda,  dA + 3072);
            const __bf16* sB = BgW + k0 + kk*32;
            const char* dB = (const char*)Bs + kk*8192 + wave*2048;
            gload16(sB,           dB);
            gload16(sB + 16*ldb,  dB + 1024);
        }
        __syncthreads();
#pragma unroll
        for (int kk = 0; kk < 2; ++kk) {
            bf16x8 af[4], bfr[8];
            #pragma unroll
            for (int i = 0; i < 4; i++)
                af[i] = *(const bf16x8*)(As + kk*8192 + (wave*64 + i*16 + lr)*32 + kg*8);
            #pragma unroll
            for (int j = 0; j < 8; j++)
                bfr[j] = *(const bf16x8*)(Bs + kk*4096 + (j*16 + lr)*32 + kg*8);
            #pragma unroll
            for (int i = 0; i < 4; i++)
                #pragma unroll
                for (int j = 0; j < 8; j++)
                    acc[i][j] = __builtin_amdgcn_mfma_f32_16x16x32_bf16(af[i], bfr[j], acc[i][j], 0, 0, 0);
        }
    }

    #pragma unroll
    for (int i = 0; i < 4; i++) {
        #pragma unroll
        for (int j = 0; j < 8; j++) {
            int row0 = bx*256 + wave*64 + i*16 + kg*4;
            if constexpr (EPI == 0) {
                if (!qkm) {
                    int col = by*128 + j*16 + lr;
                    if (col < 2048) {
                        bf16x4 vv;
                        #pragma unroll
                        for (int q = 0; q < 4; q++) vv[q] = (__bf16)silu_f(acc[i][j][q] + p.c0[col]);
                        *(bf16x4*)(p.o0 + (long)col*16384 + row0) = vv;     // vT[e][t]
                    } else {
                        #pragma unroll
                        for (int q = 0; q < 4; q++)
                            p.o1[(long)(row0+q)*2048 + (col - 2048)] = (__bf16)silu_f(acc[i][j][q] + p.c0[col]);
                    }
                } else {
                    int col = j*16 + lr;                                    // 0..127
                    float sv[4];
                    #pragma unroll
                    for (int q = 0; q < 4; q++) sv[q] = silu_f(acc[i][j][q] + p.c3[col]);
                    #pragma unroll
                    for (int q = 0; q < 4; q++) {
                        p.o2[(long)(row0+q)*128 + col] = (__bf16)(sv[q] * p.c1[      col] + p.c2[      col]);  // quad_q
                        p.o3[(long)(row0+q)*128 + col] = (__bf16)(sv[q] * p.c1[256 + col] + p.c2[256 + col]);  // quad_k
                        p.o4[(long)(row0+q)*128 + col] = (__bf16)(sv[q] * p.c1[128 + col] + p.c2[128 + col]);  // lin_q
                    }
                    bf16x4 lk;
                    #pragma unroll
                    for (int q = 0; q < 4; q++) lk[q] = (__bf16)(sv[q] * p.c1[384 + col] + p.c2[384 + col]);
                    *(bf16x4*)(p.o5 + (long)col*16384 + row0) = lk;         // lkT[d][t]
                }
            } else {   // EPI == 6
                int col = by*128 + j*16 + lr;
                #pragma unroll
                for (int q = 0; q < 4; q++) {
                    long idx = (long)(row0+q)*1024 + col;
                    p.outF[idx] = acc[i][j][q] + p.c0[col] + p.c1[idx];
                }
            }
        }
    }
}

// ---------------- merged SIM + LINKV (BK=64, one dispatch, 768 blocks) ----------------
__global__ __launch_bounds__(256, 2) void simlinkv_kernel(GP ps, GP pl) {
    __shared__ __bf16 As[2*128*32];
    __shared__ __bf16 Bs[2*128*32];
    int id = blockIdx.x;
    bool sim = id < 256;
    GP p = sim ? ps : pl;
    int bx, by, z;
    if (sim) { bx = id & 1; by = (id >> 1) & 1; z = id >> 2; }
    else     { int t = id - 256; bx = 0; by = t & 15; z = t >> 4; }

    const __bf16* A = p.A + (long)z * p.sAz + (long)bx * 128 * p.lda;
    const __bf16* B = p.B + (long)z * p.sBz + (long)by * 128 * p.ldb;
    int tid = threadIdx.x;
    int wave = tid >> 6, lane = tid & 63;
    int wr = (wave >> 1) * 64, wc = (wave & 1) * 64;
    int lr = lane & 15, kg = lane >> 4;

    f32x4 acc[4][4] = {};

    int lsub = lane >> 2;
    int scol = (lane & 3) * 8;
    const __bf16* Ag = A + scol + (long)(wave*32 + lsub) * p.lda;
    const __bf16* Bg = B + scol + (long)(wave*32 + lsub) * p.ldb;
    long a16 = (long)16 * p.lda, b16 = (long)16 * p.ldb;
    __bf16* AsW = As + wave * 32 * 32;
    __bf16* BsW = Bs + wave * 32 * 32;

    for (int ks = 0; ks < p.kSteps; ++ks) {
        long k0 = (long)ks * 64;
        __syncthreads();
        gload16(Ag + k0,            (const char*)AsW);
        gload16(Ag + k0 + a16,      (const char*)(AsW + 16*32));
        gload16(Bg + k0,            (const char*)BsW);
        gload16(Bg + k0 + b16,      (const char*)(BsW + 16*32));
        gload16(Ag + k0 + 32,       (const char*)(AsW + 4096));
        gload16(Ag + k0 + 32 + a16, (const char*)(AsW + 4096 + 16*32));
        gload16(Bg + k0 + 32,       (const char*)(BsW + 4096));
        gload16(Bg + k0 + 32 + b16, (const char*)(BsW + 4096 + 16*32));
        __syncthreads();
#pragma unroll
        for (int kk = 0; kk < 2; ++kk) {
            bf16x8 af[4], bfr[4];
            #pragma unroll
            for (int i = 0; i < 4; i++) af[i]  = *(const bf16x8*)(As + kk*4096 + (wr + i*16 + lr)*32 + kg*8);
            #pragma unroll
            for (int i = 0; i < 4; i++) bfr[i] = *(const bf16x8*)(Bs + kk*4096 + (wc + i*16 + lr)*32 + kg*8);
            #pragma unroll
            for (int i = 0; i < 4; i++)
                #pragma unroll
                for (int j = 0; j < 4; j++)
                    acc[i][j] = __builtin_amdgcn_mfma_f32_16x16x32_bf16(af[i], bfr[j], acc[i][j], 0, 0, 0);
        }
    }

    #pragma unroll
    for (int i = 0; i < 4; i++) {
        #pragma unroll
        for (int j = 0; j < 4; j++) {
            int row0 = bx*128 + wr + i*16 + kg*4;
            int col  = by*128 + wc + j*16 + lr;
            if (sim) {
                #pragma unroll
                for (int q = 0; q < 4; q++) {
                    int row = row0 + q;
                    float s = acc[i][j][q] * (1.0f/256.0f) + p.c0[row*256 + col];
                    s = fmaxf(s, 0.0f);
                    p.o0[(long)z*p.sCz + (long)row*256 + col] = (__bf16)(s * s);
                }
            } else {
                bf16x4 vv;
                #pragma unroll
                for (int q = 0; q < 4; q++) vv[q] = (__bf16)(acc[i][j][q] * p.scale);
                *(bf16x4*)(p.o0 + (long)z*p.sCz + (long)col*128 + row0) = vv;
            }
        }
    }
}

// ---------------- fused quad_out + lin_out + gate (BK=64, in-place into gate) ----------------
__global__ __launch_bounds__(256, 2) void quadlin_kernel(GP p) {
    __shared__ __bf16 As[2*128*32];
    __shared__ __bf16 Bs[2*128*32];
    int z = blockIdx.z;
    int batch = z >> 4;
    int tid = threadIdx.x;
    int wave = tid >> 6, lane = tid & 63;
    int wr = (wave >> 1) * 64, wc = (wave & 1) * 64;
    int lr = lane & 15, kg = lane >> 4;
    int lsub = lane >> 2;
    int scol = (lane & 3) * 8;
    __bf16* AsW = As + wave * 32 * 32;
    __bf16* BsW = Bs + wave * 32 * 32;

    f32x4 acc[4][4] = {};

    // pass 1: attn (lda 256) @ vT (ldb 16384), K = 256 -> 4 steps of 64
    {
        const __bf16* Ag = p.A + (long)z * 65536 + (long)blockIdx.x * 128 * 256
                         + scol + (long)(wave*32 + lsub) * 256;
        const __bf16* Bg = p.B + (long)z * 256 + (long)blockIdx.y * 128 * 16384
                         + scol + (long)(wave*32 + lsub) * 16384;
        const long a16 = 16*256, b16 = 16L*16384;
        for (int ks = 0; ks < 4; ++ks) {
            long k0 = (long)ks * 64;
            __syncthreads();
            gload16(Ag + k0,            (const char*)AsW);
            gload16(Ag + k0 + a16,      (const char*)(AsW + 16*32));
            gload16(Bg + k0,            (const char*)BsW);
            gload16(Bg + k0 + b16,      (const char*)(BsW + 16*32));
            gload16(Ag + k0 + 32,       (const char*)(AsW + 4096));
            gload16(Ag + k0 + 32 + a16, (const char*)(AsW + 4096 + 16*32));
            gload16(Bg + k0 + 32,       (const char*)(BsW + 4096));
            gload16(Bg + k0 + 32 + b16, (const char*)(BsW + 4096 + 16*32));
            __syncthreads();
#pragma unroll
            for (int kk = 0; kk < 2; ++kk) {
                bf16x8 af[4], bfr[4];
                #pragma unroll
                for (int i = 0; i < 4; i++) af[i]  = *(const bf16x8*)(As + kk*4096 + (wr + i*16 + lr)*32 + kg*8);
                #pragma unroll
                for (int i = 0; i < 4; i++) bfr[i] = *(const bf16x8*)(Bs + kk*4096 + (wc + i*16 + lr)*32 + kg*8);
                #pragma unroll
                for (int i = 0; i < 4; i++)
                    #pragma unroll
                    for (int j = 0; j < 4; j++)
                        acc[i][j] = __builtin_amdgcn_mfma_f32_16x16x32_bf16(af[i], bfr[j], acc[i][j], 0, 0, 0);
            }
        }
    }
    // pass 2: lin_q (lda 128) @ lkvT (ldb 128), K = 128 -> 2 steps of 64
    {
        const __bf16* Ag = p.A2 + ((long)z * 256 + (long)blockIdx.x * 128) * 128
                         + scol + (long)(wave*32 + lsub) * 128;
        const __bf16* Bg = p.B2 + (long)batch * 2048 * 128 + (long)blockIdx.y * 128 * 128
                         + scol + (long)(wave*32 + lsub) * 128;
        const long a16 = 16*128, b16 = 16*128;
        for (int ks = 0; ks < 2; ++ks) {
            long k0 = (long)ks * 64;
            __syncthreads();
            gload16(Ag + k0,            (const char*)AsW);
            gload16(Ag + k0 + a16,      (const char*)(AsW + 16*32));
            gload16(Bg + k0,            (const char*)BsW);
            gload16(Bg + k0 + b16,      (const char*)(BsW + 16*32));
            gload16(Ag + k0 + 32,       (const char*)(AsW + 4096));
            gload16(Ag + k0 + 32 + a16, (const char*)(AsW + 4096 + 16*32));
            gload16(Bg + k0 + 32,       (const char*)(BsW + 4096));
            gload16(Bg + k0 + 32 + b16, (const char*)(BsW + 4096 + 16*32));
            __syncthreads();
#pragma unroll
            for (int kk = 0; kk < 2; ++kk) {
                bf16x8 af[4], bfr[4];
                #pragma unroll
                for (int i = 0; i < 4; i++) af[i]  = *(const bf16x8*)(As + kk*4096 + (wr + i*16 + lr)*32 + kg*8);
                #pragma unroll
                for (int i = 0; i < 4; i++) bfr[i] = *(const bf16x8*)(Bs + kk*4096 + (wc + i*16 + lr)*32 + kg*8);
                #pragma unroll
                for (int i = 0; i < 4; i++)
                    #pragma unroll
                    for (int j = 0; j < 4; j++)
                        acc[i][j] = __builtin_amdgcn_mfma_f32_16x16x32_bf16(af[i], bfr[j], acc[i][j], 0, 0, 0);
            }
        }
    }
    #pragma unroll
    for (int i = 0; i < 4; i++) {
        #pragma unroll
        for (int j = 0; j < 4; j++) {
            int row0 = z*256 + blockIdx.x*128 + wr + i*16 + kg*4;
            int col  = blockIdx.y*128 + wc + j*16 + lr;
            #pragma unroll
            for (int q = 0; q < 4; q++) {
                long idx = (long)(row0+q)*2048 + col;
                float g = (float)p.gbuf[idx];
                p.gbuf[idx] = (__bf16)(g * acc[i][j][q]);
            }
        }
    }
}

extern "C" void kernel_launch(void* const* d_in, const int* in_sizes, int n_in,
                              void* d_out, int out_size, void* d_ws, size_t ws_size,
                              hipStream_t stream) {
    const float* x       = (const float*)d_in[0];
    const float* ln_g    = (const float*)d_in[1];
    const float* ln_b    = (const float*)d_in[2];
    const float* W_h     = (const float*)d_in[3];
    const float* b_h     = (const float*)d_in[4];
    const float* W_qk    = (const float*)d_in[5];
    const float* b_qk    = (const float*)d_in[6];
    const float* os_g    = (const float*)d_in[7];
    const float* os_b    = (const float*)d_in[8];
    const float* rel_emb = (const float*)d_in[9];
    const float* W_o     = (const float*)d_in[10];
    const float* b_o     = (const float*)d_in[11];
    float* out = (float*)d_out;

    const size_t MB = 1024 * 1024;
    if (ws_size < 190 * MB) return;

    char* ws = (char*)d_ws;
    __bf16* gate = (__bf16*)(ws + 0);          // 64 MB
    __bf16* vT   = (__bf16*)(ws + 64*MB);      // 64 MB
    __bf16* norm = (__bf16*)(ws + 128*MB);     // 32 MB (dead after hqk)
    __bf16* attn = (__bf16*)(ws + 128*MB);     //  8 MB (aliases norm)
    __bf16* lkvT = (__bf16*)(ws + 136*MB);     //  2 MB (aliases norm)
    __bf16* lkvP = (__bf16*)(ws + 140*MB);     // 16 MB split-K partials (aliases norm)
    __bf16* qq   = (__bf16*)(ws + 160*MB);
    __bf16* qk2  = (__bf16*)(ws + 164*MB);
    __bf16* lq   = (__bf16*)(ws + 168*MB);
    __bf16* lkT  = (__bf16*)(ws + 172*MB);
    float*  bmat = (float* )(ws + 176*MB);
    __bf16* WqkT = (__bf16*)(ws + 176*MB + 256*1024);
    __bf16* WoT  = (__bf16*)(ws + 177*MB);
    __bf16* WhT  = (__bf16*)(ws + 181*MB);

    // LN + weight prep + relbias, one dispatch
    prepln_kernel<<<22912, 256, 0, stream>>>(x, ln_g, ln_b, norm,
                                             W_h, W_qk, W_o, rel_emb,
                                             WhT, WqkT, WoT, bmat);

    // merged: hidden (by<32) + qk heads (by==32)   [256x128 tile]
    {
        GP p{}; p.A = norm; p.B = WhT; p.B2 = WqkT; p.lda = 1024; p.ldb = 1024; p.kSteps = 16;
        p.c0 = b_h; p.o0 = vT; p.o1 = gate;
        p.c3 = b_qk; p.c1 = os_g; p.c2 = os_b;
        p.o2 = qq; p.o3 = qk2; p.o4 = lq; p.o5 = lkT;
        g256x128_kernel<0><<<dim3(64, 33), 256, 0, stream>>>(p);
    }
    // merged: attn (256 blocks, K=128) + lin_kv split-K partials (512 blocks, K=512)
    {
        GP ps{}; ps.A = qq; ps.B = qk2; ps.lda = 128; ps.ldb = 128; ps.kSteps = 2;
        ps.sAz = 256*128; ps.sBz = 256*128; ps.sCz = 256*256;
        ps.c0 = bmat; ps.o0 = attn;
        GP pl{}; pl.A = lkT; pl.B = vT; pl.lda = 16384; pl.ldb = 16384; pl.kSteps = 8;
        pl.sAz = 512; pl.sBz = 512; pl.sCz = 2048*128; pl.scale = 1.0f/4096.0f;
        pl.o0 = lkvP;
        simlinkv_kernel<<<768, 256, 0, stream>>>(ps, pl);
    }
    reduce8_kernel<<<1024, 256, 0, stream>>>(lkvP, lkvT);
    // gate <- gate * (attn @ v + lin_q @ lin_kv)
    {
        GP p{}; p.A = attn; p.B = vT; p.A2 = lq; p.B2 = lkvT; p.gbuf = gate;
        quadlin_kernel<<<dim3(2, 16, 64), 256, 0, stream>>>(p);
    }
    // final = combined @ W_o + b_o + x   [256x128 tile]
    {
        GP p{}; p.A = gate; p.B = WoT; p.lda = 2048; p.ldb = 2048; p.kSteps = 32;
        p.c0 = b_o; p.c1 = x; p.outF = out;
        g256x128_kernel<6><<<dim3(64, 8), 256, 0, stream>>>(p);
    }
}

// Round 15
// 406.800 us; speedup vs baseline: 1.8278x; 1.8278x over previous
//
#include <hip/hip_runtime.h>
#include <hip/hip_bf16.h>

typedef float  f32x4  __attribute__((ext_vector_type(4)));
typedef __bf16 bf16x8 __attribute__((ext_vector_type(8)));
typedef __bf16 bf16x4 __attribute__((ext_vector_type(4)));

__device__ __forceinline__ float silu_f(float x) { return x / (1.0f + __expf(-x)); }

__device__ __forceinline__ void gload16(const __bf16* g, const char* lds) {
    __builtin_amdgcn_global_load_lds((const __attribute__((address_space(1))) void*)g,
                                     (__attribute__((address_space(3))) void*)lds, 16, 0, 0);
}

// ---------------- merged LN + weight transposes + rel-bias ----------------
__global__ __launch_bounds__(256) void prepln_kernel(const float* __restrict__ x,
                                                     const float* __restrict__ ln_g,
                                                     const float* __restrict__ ln_b,
                                                     __bf16* __restrict__ norm,
                                                     const float* __restrict__ W_h,
                                                     const float* __restrict__ W_qk,
                                                     const float* __restrict__ W_o,
                                                     const float* __restrict__ rel_emb,
                                                     __bf16* __restrict__ WhT,
                                                     __bf16* __restrict__ WqkT,
                                                     __bf16* __restrict__ WoT,
                                                     float* __restrict__ bmat) {
    __shared__ float red[8];
    __shared__ __bf16 tile[32][33];
    int id = blockIdx.x, tid = threadIdx.x;
    if (id < 16384) {                       // LayerNorm
        const float* xr = x + (long)id * 1024;
        f32x4 v = *(const f32x4*)(xr + tid * 4);
        float s  = v[0] + v[1] + v[2] + v[3];
        float ss = v[0]*v[0] + v[1]*v[1] + v[2]*v[2] + v[3]*v[3];
        #pragma unroll
        for (int off = 32; off > 0; off >>= 1) {
            s  += __shfl_down(s, off);
            ss += __shfl_down(ss, off);
        }
        int wave = tid >> 6, lane = tid & 63;
        if (lane == 0) { red[wave*2] = s; red[wave*2+1] = ss; }
        __syncthreads();
        float S  = red[0] + red[2] + red[4] + red[6];
        float SS = red[1] + red[3] + red[5] + red[7];
        float mean = S * (1.0f/1024.0f);
        float var  = SS * (1.0f/1024.0f) - mean*mean;
        float rstd = rsqrtf(var + 1e-5f);
        __bf16* orow = norm + (long)id * 1024;
        #pragma unroll
        for (int j = 0; j < 4; j++) {
            float fv = (v[j] - mean) * rstd * ln_g[tid*4+j] + ln_b[tid*4+j];
            orow[tid*4+j] = (__bf16)fv;
        }
        return;
    }
    id -= 16384;
    if (id >= 6272) {                       // relbias
        int idx = (id - 6272) * 256 + tid;
        int i = idx >> 8, j = idx & 255;
        int n = i - j;
        int ret = (n < 0) ? 16 : 0;
        int an = (n < 0) ? -n : n;
        int bucket;
        if (an < 8) {
            bucket = ret + an;
        } else {
            float vl = logf((float)an * 0.125f) / 2.772588722239781f * 8.0f;
            int lv = 8 + (int)vl;
            bucket = ret + (lv < 15 ? lv : 15);
        }
        bmat[idx] = rel_emb[bucket] * 11.313708498984761f;
        return;
    }
    const float* in; __bf16* outp; int rows, cols, tx, ty;
    if (id < 4096)      { in = W_h;  outp = WhT;  rows = 1024; cols = 4096; tx = id % 128; ty = id / 128; }
    else if (id < 4224) { int t = id - 4096; in = W_qk; outp = WqkT; rows = 1024; cols = 128;  tx = t % 4;  ty = t / 4; }
    else                { int t = id - 4224; in = W_o;  outp = WoT;  rows = 2048; cols = 1024; tx = t % 32; ty = t / 32; }
    int c0 = tx * 32, r0 = ty * 32;
    int lx = tid & 31, ly = tid >> 5;
    #pragma unroll
    for (int i = 0; i < 4; i++) {
        int r = ly + i*8;
        tile[r][lx] = (__bf16)in[(long)(r0 + r) * cols + c0 + lx];
    }
    __syncthreads();
    #pragma unroll
    for (int i = 0; i < 4; i++) {
        int c = ly + i*8;
        outp[(long)(c0 + c) * rows + r0 + lx] = tile[lx][c];
    }
}

// ---------------- reduce 8 bf16 partials -> bf16 ----------------
__global__ __launch_bounds__(256) void reduce8_kernel(const __bf16* __restrict__ in,
                                                      __bf16* __restrict__ out) {
    int i = (blockIdx.x * 256 + threadIdx.x) * 4;
    int b = i >> 18;
    int r = i & 262143;
    float s0 = 0.f, s1 = 0.f, s2 = 0.f, s3 = 0.f;
    #pragma unroll
    for (int c = 0; c < 8; ++c) {
        bf16x4 v = *(const bf16x4*)(in + ((long)(b*8 + c) << 18) + r);
        s0 += (float)v[0]; s1 += (float)v[1]; s2 += (float)v[2]; s3 += (float)v[3];
    }
    bf16x4 o; o[0] = (__bf16)s0; o[1] = (__bf16)s1; o[2] = (__bf16)s2; o[3] = (__bf16)s3;
    *(bf16x4*)(out + i) = o;
}

// ---------------- GP param block ----------------
struct GP {
    const __bf16* A;
    const __bf16* B;
    const __bf16* A2;
    const __bf16* B2;
    int lda, ldb, kSteps;
    long sAz, sBz, sCz;
    float scale;
    float* outF;
    __bf16 *o0, *o1, *o2, *o3, *o4, *o5;
    const float *c0, *c1, *c2, *c3;
    __bf16* gbuf;
};

// ================= merged H + QK GEMM (128x128, BK=64), grid (128, 33) =================
// L2-blocking XCD map: xcd = id&7 owns bx in [xcd*16, xcd*16+16) and iterates by.
__global__ __launch_bounds__(256, 2) void hqk_kernel(GP p) {
    __shared__ __bf16 As[2*128*32];
    __shared__ __bf16 Bs[2*128*32];
    int id = blockIdx.y * 128 + blockIdx.x;
    int xcd = id & 7, seq = id >> 3;        // seq 0..527
    int by = seq >> 4;                      // 0..32
    int bx = (xcd << 4) | (seq & 15);       // 0..127
    bool qkm = (by == 32);
    const __bf16* A = p.A + (long)bx * 128 * 1024;
    const __bf16* B = qkm ? p.B2 : p.B + (long)by * 128 * 1024;
    int tid = threadIdx.x;
    int wave = tid >> 6, lane = tid & 63;
    int wr = (wave >> 1) * 64, wc = (wave & 1) * 64;
    int lr = lane & 15, kg = lane >> 4;

    f32x4 acc[4][4] = {};

    int lsub = lane >> 2;
    int scol = (lane & 3) * 8;
    const __bf16* Ag = A + scol + (long)(wave*32 + lsub) * 1024;
    const __bf16* Bg = B + scol + (long)(wave*32 + lsub) * 1024;
    const long s16 = 16 * 1024;
    __bf16* AsW = As + wave * 32 * 32;
    __bf16* BsW = Bs + wave * 32 * 32;

    for (int ks = 0; ks < 16; ++ks) {
        long k0 = (long)ks * 64;
        __syncthreads();
        gload16(Ag + k0,            (const char*)AsW);
        gload16(Ag + k0 + s16,      (const char*)(AsW + 16*32));
        gload16(Bg + k0,            (const char*)BsW);
        gload16(Bg + k0 + s16,      (const char*)(BsW + 16*32));
        gload16(Ag + k0 + 32,       (const char*)(AsW + 4096));
        gload16(Ag + k0 + 32 + s16, (const char*)(AsW + 4096 + 16*32));
        gload16(Bg + k0 + 32,       (const char*)(BsW + 4096));
        gload16(Bg + k0 + 32 + s16, (const char*)(BsW + 4096 + 16*32));
        __syncthreads();
#pragma unroll
        for (int kk = 0; kk < 2; ++kk) {
            bf16x8 af[4], bfr[4];
            #pragma unroll
            for (int i = 0; i < 4; i++) af[i]  = *(const bf16x8*)(As + kk*4096 + (wr + i*16 + lr)*32 + kg*8);
            #pragma unroll
            for (int i = 0; i < 4; i++) bfr[i] = *(const bf16x8*)(Bs + kk*4096 + (wc + i*16 + lr)*32 + kg*8);
            #pragma unroll
            for (int i = 0; i < 4; i++)
                #pragma unroll
                for (int j = 0; j < 4; j++)
                    acc[i][j] = __builtin_amdgcn_mfma_f32_16x16x32_bf16(af[i], bfr[j], acc[i][j], 0, 0, 0);
        }
    }

    #pragma unroll
    for (int i = 0; i < 4; i++) {
        #pragma unroll
        for (int j = 0; j < 4; j++) {
            int row0 = bx*128 + wr + i*16 + kg*4;
            if (!qkm) {
                int col = by*128 + wc + j*16 + lr;
                if (col < 2048) {
                    bf16x4 vv;
                    #pragma unroll
                    for (int q = 0; q < 4; q++) vv[q] = (__bf16)silu_f(acc[i][j][q] + p.c0[col]);
                    *(bf16x4*)(p.o0 + (long)col*16384 + row0) = vv;     // vT[e][t]
                } else {
                    #pragma unroll
                    for (int q = 0; q < 4; q++)
                        p.o1[(long)(row0+q)*2048 + (col - 2048)] = (__bf16)silu_f(acc[i][j][q] + p.c0[col]);
                }
            } else {
                int col = wc + j*16 + lr;                               // 0..127
                float sv[4];
                #pragma unroll
                for (int q = 0; q < 4; q++) sv[q] = silu_f(acc[i][j][q] + p.c3[col]);
                #pragma unroll
                for (int q = 0; q < 4; q++) {
                    p.o2[(long)(row0+q)*128 + col] = (__bf16)(sv[q] * p.c1[      col] + p.c2[      col]);  // quad_q
                    p.o3[(long)(row0+q)*128 + col] = (__bf16)(sv[q] * p.c1[256 + col] + p.c2[256 + col]);  // quad_k
                    p.o4[(long)(row0+q)*128 + col] = (__bf16)(sv[q] * p.c1[128 + col] + p.c2[128 + col]);  // lin_q
                }
                bf16x4 lk;
                #pragma unroll
                for (int q = 0; q < 4; q++) lk[q] = (__bf16)(sv[q] * p.c1[384 + col] + p.c2[384 + col]);
                *(bf16x4*)(p.o5 + (long)col*16384 + row0) = lk;         // lkT[d][t]
            }
        }
    }
}

// ================= 128x128 GEMM BK=64 — FINAL epilogue, L2-blocked XCD map =================
__global__ __launch_bounds__(256, 2) void gemm64f_kernel(GP p) {
    __shared__ __bf16 As[2*128*32];
    __shared__ __bf16 Bs[2*128*32];
    int id = blockIdx.y * 128 + blockIdx.x;
    int xcd = id & 7, seq = id >> 3;        // seq 0..127
    int grp = seq >> 6;                     // 0..1
    int by  = (seq >> 3) & 7;               // 0..7
    int bx  = (xcd << 4) | (grp << 3) | (seq & 7);   // 0..127
    const __bf16* A = p.A + (long)bx * 128 * p.lda;
    const __bf16* B = p.B + (long)by * 128 * p.ldb;
    int tid = threadIdx.x;
    int wave = tid >> 6, lane = tid & 63;
    int wr = (wave >> 1) * 64, wc = (wave & 1) * 64;
    int lr = lane & 15, kg = lane >> 4;

    f32x4 acc[4][4] = {};

    int lsub = lane >> 2;
    int scol = (lane & 3) * 8;
    const __bf16* Ag = A + scol + (long)(wave*32 + lsub) * p.lda;
    const __bf16* Bg = B + scol + (long)(wave*32 + lsub) * p.ldb;
    long a16 = (long)16 * p.lda, b16 = (long)16 * p.ldb;
    __bf16* AsW = As + wave * 32 * 32;
    __bf16* BsW = Bs + wave * 32 * 32;

    for (int ks = 0; ks < p.kSteps; ++ks) {
        long k0 = (long)ks * 64;
        __syncthreads();
        gload16(Ag + k0,            (const char*)AsW);
        gload16(Ag + k0 + a16,      (const char*)(AsW + 16*32));
        gload16(Bg + k0,            (const char*)BsW);
        gload16(Bg + k0 + b16,      (const char*)(BsW + 16*32));
        gload16(Ag + k0 + 32,       (const char*)(AsW + 4096));
        gload16(Ag + k0 + 32 + a16, (const char*)(AsW + 4096 + 16*32));
        gload16(Bg + k0 + 32,       (const char*)(BsW + 4096));
        gload16(Bg + k0 + 32 + b16, (const char*)(BsW + 4096 + 16*32));
        __syncthreads();
#pragma unroll
        for (int kk = 0; kk < 2; ++kk) {
            bf16x8 af[4], bfr[4];
            #pragma unroll
            for (int i = 0; i < 4; i++) af[i]  = *(const bf16x8*)(As + kk*4096 + (wr + i*16 + lr)*32 + kg*8);
            #pragma unroll
            for (int i = 0; i < 4; i++) bfr[i] = *(const bf16x8*)(Bs + kk*4096 + (wc + i*16 + lr)*32 + kg*8);
            #pragma unroll
            for (int i = 0; i < 4; i++)
                #pragma unroll
                for (int j = 0; j < 4; j++)
                    acc[i][j] = __builtin_amdgcn_mfma_f32_16x16x32_bf16(af[i], bfr[j], acc[i][j], 0, 0, 0);
        }
    }

    #pragma unroll
    for (int i = 0; i < 4; i++) {
        #pragma unroll
        for (int j = 0; j < 4; j++) {
            int row0 = bx*128 + wr + i*16 + kg*4;
            int col  = by*128 + wc + j*16 + lr;
            #pragma unroll
            for (int q = 0; q < 4; q++) {
                long idx = (long)(row0+q)*1024 + col;
                p.outF[idx] = acc[i][j][q] + p.c0[col] + p.c1[idx];
            }
        }
    }
}

// ---------------- merged SIM + LINKV (BK=64, one dispatch, 768 blocks) ----------------
__global__ __launch_bounds__(256, 2) void simlinkv_kernel(GP ps, GP pl) {
    __shared__ __bf16 As[2*128*32];
    __shared__ __bf16 Bs[2*128*32];
    int id = blockIdx.x;
    bool sim = id < 256;
    GP p = sim ? ps : pl;
    int bx, by, z;
    if (sim) { bx = id & 1; by = (id >> 1) & 1; z = id >> 2; }
    else     { int t = id - 256; bx = 0; by = t & 15; z = t >> 4; }

    const __bf16* A = p.A + (long)z * p.sAz + (long)bx * 128 * p.lda;
    const __bf16* B = p.B + (long)z * p.sBz + (long)by * 128 * p.ldb;
    int tid = threadIdx.x;
    int wave = tid >> 6, lane = tid & 63;
    int wr = (wave >> 1) * 64, wc = (wave & 1) * 64;
    int lr = lane & 15, kg = lane >> 4;

    f32x4 acc[4][4] = {};

    int lsub = lane >> 2;
    int scol = (lane & 3) * 8;
    const __bf16* Ag = A + scol + (long)(wave*32 + lsub) * p.lda;
    const __bf16* Bg = B + scol + (long)(wave*32 + lsub) * p.ldb;
    long a16 = (long)16 * p.lda, b16 = (long)16 * p.ldb;
    __bf16* AsW = As + wave * 32 * 32;
    __bf16* BsW = Bs + wave * 32 * 32;

    for (int ks = 0; ks < p.kSteps; ++ks) {
        long k0 = (long)ks * 64;
        __syncthreads();
        gload16(Ag + k0,            (const char*)AsW);
        gload16(Ag + k0 + a16,      (const char*)(AsW + 16*32));
        gload16(Bg + k0,            (const char*)BsW);
        gload16(Bg + k0 + b16,      (const char*)(BsW + 16*32));
        gload16(Ag + k0 + 32,       (const char*)(AsW + 4096));
        gload16(Ag + k0 + 32 + a16, (const char*)(AsW + 4096 + 16*32));
        gload16(Bg + k0 + 32,       (const char*)(BsW + 4096));
        gload16(Bg + k0 + 32 + b16, (const char*)(BsW + 4096 + 16*32));
        __syncthreads();
#pragma unroll
        for (int kk = 0; kk < 2; ++kk) {
            bf16x8 af[4], bfr[4];
            #pragma unroll
            for (int i = 0; i < 4; i++) af[i]  = *(const bf16x8*)(As + kk*4096 + (wr + i*16 + lr)*32 + kg*8);
            #pragma unroll
            for (int i = 0; i < 4; i++) bfr[i] = *(const bf16x8*)(Bs + kk*4096 + (wc + i*16 + lr)*32 + kg*8);
            #pragma unroll
            for (int i = 0; i < 4; i++)
                #pragma unroll
                for (int j = 0; j < 4; j++)
                    acc[i][j] = __builtin_amdgcn_mfma_f32_16x16x32_bf16(af[i], bfr[j], acc[i][j], 0, 0, 0);
        }
    }

    #pragma unroll
    for (int i = 0; i < 4; i++) {
        #pragma unroll
        for (int j = 0; j < 4; j++) {
            int row0 = bx*128 + wr + i*16 + kg*4;
            int col  = by*128 + wc + j*16 + lr;
            if (sim) {
                #pragma unroll
                for (int q = 0; q < 4; q++) {
                    int row = row0 + q;
                    float s = acc[i][j][q] * (1.0f/256.0f) + p.c0[row*256 + col];
                    s = fmaxf(s, 0.0f);
                    p.o0[(long)z*p.sCz + (long)row*256 + col] = (__bf16)(s * s);
                }
            } else {
                bf16x4 vv;
                #pragma unroll
                for (int q = 0; q < 4; q++) vv[q] = (__bf16)(acc[i][j][q] * p.scale);
                *(bf16x4*)(p.o0 + (long)z*p.sCz + (long)col*128 + row0) = vv;
            }
        }
    }
}

// ---------------- fused quad_out + lin_out + gate (BK=64, in-place into gate) ----------------
__global__ __launch_bounds__(256, 2) void quadlin_kernel(GP p) {
    __shared__ __bf16 As[2*128*32];
    __shared__ __bf16 Bs[2*128*32];
    int z = blockIdx.z;
    int batch = z >> 4;
    int tid = threadIdx.x;
    int wave = tid >> 6, lane = tid & 63;
    int wr = (wave >> 1) * 64, wc = (wave & 1) * 64;
    int lr = lane & 15, kg = lane >> 4;
    int lsub = lane >> 2;
    int scol = (lane & 3) * 8;
    __bf16* AsW = As + wave * 32 * 32;
    __bf16* BsW = Bs + wave * 32 * 32;

    f32x4 acc[4][4] = {};

    // pass 1: attn (lda 256) @ vT (ldb 16384), K = 256 -> 4 steps of 64
    {
        const __bf16* Ag = p.A + (long)z * 65536 + (long)blockIdx.x * 128 * 256
                         + scol + (long)(wave*32 + lsub) * 256;
        const __bf16* Bg = p.B + (long)z * 256 + (long)blockIdx.y * 128 * 16384
                         + scol + (long)(wave*32 + lsub) * 16384;
        const long a16 = 16*256, b16 = 16L*16384;
        for (int ks = 0; ks < 4; ++ks) {
            long k0 = (long)ks * 64;
            __syncthreads();
            gload16(Ag + k0,            (const char*)AsW);
            gload16(Ag + k0 + a16,      (const char*)(AsW + 16*32));
            gload16(Bg + k0,            (const char*)BsW);
            gload16(Bg + k0 + b16,      (const char*)(BsW + 16*32));
            gload16(Ag + k0 + 32,       (const char*)(AsW + 4096));
            gload16(Ag + k0 + 32 + a16, (const char*)(AsW + 4096 + 16*32));
            gload16(Bg + k0 + 32,       (const char*)(BsW + 4096));
            gload16(Bg + k0 + 32 + b16, (const char*)(BsW + 4096 + 16*32));
            __syncthreads();
#pragma unroll
            for (int kk = 0; kk < 2; ++kk) {
                bf16x8 af[4], bfr[4];
                #pragma unroll
                for (int i = 0; i < 4; i++) af[i]  = *(const bf16x8*)(As + kk*4096 + (wr + i*16 + lr)*32 + kg*8);
                #pragma unroll
                for (int i = 0; i < 4; i++) bfr[i] = *(const bf16x8*)(Bs + kk*4096 + (wc + i*16 + lr)*32 + kg*8);
                #pragma unroll
                for (int i = 0; i < 4; i++)
                    #pragma unroll
                    for (int j = 0; j < 4; j++)
                        acc[i][j] = __builtin_amdgcn_mfma_f32_16x16x32_bf16(af[i], bfr[j], acc[i][j], 0, 0, 0);
            }
        }
    }
    // pass 2: lin_q (lda 128) @ lkvT (ldb 128), K = 128 -> 2 steps of 64
    {
        const __bf16* Ag = p.A2 + ((long)z * 256 + (long)blockIdx.x * 128) * 128
                         + scol + (long)(wave*32 + lsub) * 128;
        const __bf16* Bg = p.B2 + (long)batch * 2048 * 128 + (long)blockIdx.y * 128 * 128
                         + scol + (long)(wave*32 + lsub) * 128;
        const long a16 = 16*128, b16 = 16*128;
        for (int ks = 0; ks < 2; ++ks) {
            long k0 = (long)ks * 64;
            __syncthreads();
            gload16(Ag + k0,            (const char*)AsW);
            gload16(Ag + k0 + a16,      (const char*)(AsW + 16*32));
            gload16(Bg + k0,            (const char*)BsW);
            gload16(Bg + k0 + b16,      (const char*)(BsW + 16*32));
            gload16(Ag + k0 + 32,       (const char*)(AsW + 4096));
            gload16(Ag + k0 + 32 + a16, (const char*)(AsW + 4096 + 16*32));
            gload16(Bg + k0 + 32,       (const char*)(BsW + 4096));
            gload16(Bg + k0 + 32 + b16, (const char*)(BsW + 4096 + 16*32));
            __syncthreads();
#pragma unroll
            for (int kk = 0; kk < 2; ++kk) {
                bf16x8 af[4], bfr[4];
                #pragma unroll
                for (int i = 0; i < 4; i++) af[i]  = *(const bf16x8*)(As + kk*4096 + (wr + i*16 + lr)*32 + kg*8);
                #pragma unroll
                for (int i = 0; i < 4; i++) bfr[i] = *(const bf16x8*)(Bs + kk*4096 + (wc + i*16 + lr)*32 + kg*8);
                #pragma unroll
                for (int i = 0; i < 4; i++)
                    #pragma unroll
                    for (int j = 0; j < 4; j++)
                        acc[i][j] = __builtin_amdgcn_mfma_f32_16x16x32_bf16(af[i], bfr[j], acc[i][j], 0, 0, 0);
            }
        }
    }
    #pragma unroll
    for (int i = 0; i < 4; i++) {
        #pragma unroll
        for (int j = 0; j < 4; j++) {
            int row0 = z*256 + blockIdx.x*128 + wr + i*16 + kg*4;
            int col  = blockIdx.y*128 + wc + j*16 + lr;
            #pragma unroll
            for (int q = 0; q < 4; q++) {
                long idx = (long)(row0+q)*2048 + col;
                float g = (float)p.gbuf[idx];
                p.gbuf[idx] = (__bf16)(g * acc[i][j][q]);
            }
        }
    }
}

extern "C" void kernel_launch(void* const* d_in, const int* in_sizes, int n_in,
                              void* d_out, int out_size, void* d_ws, size_t ws_size,
                              hipStream_t stream) {
    const float* x       = (const float*)d_in[0];
    const float* ln_g    = (const float*)d_in[1];
    const float* ln_b    = (const float*)d_in[2];
    const float* W_h     = (const float*)d_in[3];
    const float* b_h     = (const float*)d_in[4];
    const float* W_qk    = (const float*)d_in[5];
    const float* b_qk    = (const float*)d_in[6];
    const float* os_g    = (const float*)d_in[7];
    const float* os_b    = (const float*)d_in[8];
    const float* rel_emb = (const float*)d_in[9];
    const float* W_o     = (const float*)d_in[10];
    const float* b_o     = (const float*)d_in[11];
    float* out = (float*)d_out;

    const size_t MB = 1024 * 1024;
    if (ws_size < 190 * MB) return;

    char* ws = (char*)d_ws;
    __bf16* gate = (__bf16*)(ws + 0);          // 64 MB
    __bf16* vT   = (__bf16*)(ws + 64*MB);      // 64 MB
    __bf16* norm = (__bf16*)(ws + 128*MB);     // 32 MB (dead after hqk)
    __bf16* attn = (__bf16*)(ws + 128*MB);     //  8 MB (aliases norm)
    __bf16* lkvT = (__bf16*)(ws + 136*MB);     //  2 MB (aliases norm)
    __bf16* lkvP = (__bf16*)(ws + 140*MB);     // 16 MB split-K partials (aliases norm)
    __bf16* qq   = (__bf16*)(ws + 160*MB);
    __bf16* qk2  = (__bf16*)(ws + 164*MB);
    __bf16* lq   = (__bf16*)(ws + 168*MB);
    __bf16* lkT  = (__bf16*)(ws + 172*MB);
    float*  bmat = (float* )(ws + 176*MB);
    __bf16* WqkT = (__bf16*)(ws + 176*MB + 256*1024);
    __bf16* WoT  = (__bf16*)(ws + 177*MB);
    __bf16* WhT  = (__bf16*)(ws + 181*MB);

    // LN + weight prep + relbias, one dispatch
    prepln_kernel<<<22912, 256, 0, stream>>>(x, ln_g, ln_b, norm,
                                             W_h, W_qk, W_o, rel_emb,
                                             WhT, WqkT, WoT, bmat);

    // merged: hidden (by<32) + qk heads (by==32), L2-blocked XCD map
    {
        GP p{}; p.A = norm; p.B = WhT; p.B2 = WqkT;
        p.c0 = b_h; p.o0 = vT; p.o1 = gate;
        p.c3 = b_qk; p.c1 = os_g; p.c2 = os_b;
        p.o2 = qq; p.o3 = qk2; p.o4 = lq; p.o5 = lkT;
        hqk_kernel<<<dim3(128, 33), 256, 0, stream>>>(p);
    }
    // merged: attn (256 blocks, K=128) + lin_kv split-K partials (512 blocks, K=512)
    {
        GP ps{}; ps.A = qq; ps.B = qk2; ps.lda = 128; ps.ldb = 128; ps.kSteps = 2;
        ps.sAz = 256*128; ps.sBz = 256*128; ps.sCz = 256*256;
        ps.c0 = bmat; ps.o0 = attn;
        GP pl{}; pl.A = lkT; pl.B = vT; pl.lda = 16384; pl.ldb = 16384; pl.kSteps = 8;
        pl.sAz = 512; pl.sBz = 512; pl.sCz = 2048*128; pl.scale = 1.0f/4096.0f;
        pl.o0 = lkvP;
        simlinkv_kernel<<<768, 256, 0, stream>>>(ps, pl);
    }
    reduce8_kernel<<<1024, 256, 0, stream>>>(lkvP, lkvT);
    // gate <- gate * (attn @ v + lin_q @ lin_kv)
    {
        GP p{}; p.A = attn; p.B = vT; p.A2 = lq; p.B2 = lkvT; p.gbuf = gate;
        quadlin_kernel<<<dim3(2, 16, 64), 256, 0, stream>>>(p);
    }
    // final = combined @ W_o + b_o + x   [128^2 BK=64, L2-blocked XCD map]
    {
        GP p{}; p.A = gate; p.B = WoT; p.lda = 2048; p.ldb = 2048; p.kSteps = 32;
        p.c0 = b_o; p.c1 = x; p.outF = out;
        gemm64f_kernel<<<dim3(128, 8), 256, 0, stream>>>(p);
    }
}